// Round 8
// baseline (352.981 us; speedup 1.0000x reference)
//
#include <hip/hip_runtime.h>
#include <hip/hip_bf16.h>
#include <math.h>

typedef short bf16x8 __attribute__((ext_vector_type(8)));
typedef short bf16x4 __attribute__((ext_vector_type(4)));
typedef float f32x4 __attribute__((ext_vector_type(4)));

__device__ inline unsigned short f2bf(float f) {
  unsigned u = __float_as_uint(f);
  u += 0x7FFF + ((u >> 16) & 1);           // RNE
  return (unsigned short)(u >> 16);
}
__device__ inline float bf2f(unsigned short h) {
  return __uint_as_float(((unsigned)h) << 16);
}
__device__ inline float bflo(unsigned u) { return __uint_as_float(u << 16); }
__device__ inline float bfhi(unsigned u) { return __uint_as_float(u & 0xffff0000u); }

// ---------------- CSR build ----------------

__global__ __launch_bounds__(256) void count_k(const int* __restrict__ dst, int* __restrict__ cnt, int e) {
  int i = blockIdx.x * 256 + threadIdx.x;
  if (i < e) atomicAdd(&cnt[dst[i]], 1);
}

__global__ __launch_bounds__(256) void scan_a(const int* __restrict__ cnt, int* __restrict__ bsum, int n) {
  int i = blockIdx.x * 256 + threadIdx.x;
  int v = (i < n) ? cnt[i] : 0;
#pragma unroll
  for (int o = 32; o > 0; o >>= 1) v += __shfl_xor(v, o);
  __shared__ int ws[4];
  if ((threadIdx.x & 63) == 0) ws[threadIdx.x >> 6] = v;
  __syncthreads();
  if (threadIdx.x == 0) bsum[blockIdx.x] = ws[0] + ws[1] + ws[2] + ws[3];
}

__global__ __launch_bounds__(256) void scan_b(const int* __restrict__ bsum, int* __restrict__ bpre,
                                              int* __restrict__ off_n, int nb) {
  __shared__ int s[256];
  int t = threadIdx.x;
  int v = (t < nb) ? bsum[t] : 0;
  s[t] = v;
  __syncthreads();
  for (int o = 1; o < 256; o <<= 1) {
    int u = (t >= o) ? s[t - o] : 0;
    __syncthreads();
    s[t] += u;
    __syncthreads();
  }
  if (t < nb) bpre[t] = s[t] - v;
  if (t == 255) off_n[0] = s[255];
}

// scan_c also computes dis = rsqrt(cnt+1)
__global__ __launch_bounds__(256) void scan_c(const int* __restrict__ cnt, const int* __restrict__ bpre,
                                              int* __restrict__ off, int* __restrict__ cursor,
                                              float* __restrict__ dis, int n) {
  __shared__ int s[256];
  int i = blockIdx.x * 256 + threadIdx.x;
  int t = threadIdx.x;
  int v = (i < n) ? cnt[i] : 0;
  s[t] = v;
  __syncthreads();
  for (int o = 1; o < 256; o <<= 1) {
    int u = (t >= o) ? s[t - o] : 0;
    __syncthreads();
    s[t] += u;
    __syncthreads();
  }
  if (i < n) {
    int ov = bpre[blockIdx.x] + s[t] - v;
    off[i] = ov;
    cursor[i] = ov;
    dis[i] = rsqrtf((float)v + 1.0f);
  }
}

__global__ __launch_bounds__(256) void scatter_k(const int* __restrict__ src, const int* __restrict__ dst,
                                                 int* __restrict__ cursor, int* __restrict__ csr, int e) {
  int i = blockIdx.x * 256 + threadIdx.x;
  if (i < e) {
    int p = atomicAdd(&cursor[dst[i]], 1);
    csr[p] = src[i];
  }
}

// ------- weight convert: W[K][N] fp32 -> Wc[N][K] bf16 -------

__global__ __launch_bounds__(256) void wconv_k(const float* __restrict__ W1, const float* __restrict__ Wr,
                                               const float* __restrict__ W2, const float* __restrict__ W3,
                                               const float* __restrict__ W4,
                                               short* __restrict__ o1, short* __restrict__ oR,
                                               short* __restrict__ o2, short* __restrict__ o3,
                                               short* __restrict__ o4) {
  int b = blockIdx.x;  // 960 rows total
  const float* W; short* O; int K, N, nr;
  if (b < 64)       { W = W1; O = o1; K = 128; N = 64;  nr = b; }
  else if (b < 128) { W = Wr; O = oR; K = 128; N = 64;  nr = b - 64; }
  else if (b < 384) { W = W2; O = o2; K = 64;  N = 256; nr = b - 128; }
  else if (b < 896) { W = W3; O = o3; K = 256; N = 512; nr = b - 384; }
  else              { W = W4; O = o4; K = 512; N = 64;  nr = b - 896; }
  for (int k = threadIdx.x; k < K; k += 256)
    O[(size_t)nr * K + k] = (short)f2bf(W[(size_t)k * N + nr]);
}

// ------- MFMA GEMM (generic): C[M,NTOT] = A[M,KT] @ Wc[NTOT,KT](bf16) -------

template<int KT, int NTOT, int WM, int WN, int BIAS, int RELU, int ABF, int OBF, int SPLIT, int SCL, int BLK>
__global__ __launch_bounds__(256, BLK) void mgemm(const void* __restrict__ Av,
                                                  const short* __restrict__ Wc,
                                                  const float* __restrict__ bias,
                                                  void* __restrict__ Cv, void* __restrict__ Cv2,
                                                  const float* __restrict__ scl, int M) {
  __shared__ short As[64 * WM][ABF ? 40 : 72];
  __shared__ short Bs[64 * WN][40];
  const int tid = threadIdx.x;
  const int row0 = blockIdx.x * (64 * WM);
  const int col0 = blockIdx.y * (64 * WN);
  const int w = tid >> 6, lane = tid & 63;
  const int wm = w / WN, wn = w % WN;
  const int rm = wm * 64, cn = wn * 64;
  const int lm = lane & 15, lk = (lane >> 4) * 8;

  f32x4 acc[4][4];
#pragma unroll
  for (int i = 0; i < 4; i++)
#pragma unroll
    for (int j = 0; j < 4; j++)
#pragma unroll
      for (int r = 0; r < 4; r++) acc[i][j][r] = 0.f;

  for (int k0 = 0; k0 < KT; k0 += 32) {
#pragma unroll
    for (int p = 0; p < WM; p++) {
      int r = (tid >> 2) + p * 64;
      int kseg = (tid & 3) * 8;
      int gr = row0 + r;
      if (ABF) {
        bf16x8 v = {0, 0, 0, 0, 0, 0, 0, 0};
        if (gr < M) v = *(const bf16x8*)((const short*)Av + (size_t)gr * KT + k0 + kseg);
        *(bf16x8*)&As[r][kseg] = v;
      } else {
        float4 v0 = {0.f, 0.f, 0.f, 0.f}, v1 = {0.f, 0.f, 0.f, 0.f};
        if (gr < M) {
          const float* ap = (const float*)Av + (size_t)gr * KT + k0 + kseg;
          v0 = *(const float4*)ap;
          v1 = *(const float4*)(ap + 4);
        }
        float vv[8] = {v0.x, v0.y, v0.z, v0.w, v1.x, v1.y, v1.z, v1.w};
        bf16x8 hv, lv;
#pragma unroll
        for (int j = 0; j < 8; j++) {
          unsigned short h = f2bf(vv[j]);
          hv[j] = (short)h;
          lv[j] = (short)f2bf(vv[j] - bf2f(h));
        }
        *(bf16x8*)&As[r][kseg] = hv;
        *(bf16x8*)&As[r][32 + kseg] = lv;
      }
    }
#pragma unroll
    for (int p = 0; p < WN; p++) {
      int nr = (tid >> 2) + p * 64;
      int seg = (tid & 3) * 8;
      *(bf16x8*)&Bs[nr][seg] = *(const bf16x8*)(Wc + (size_t)(col0 + nr) * KT + k0 + seg);
    }
    __syncthreads();

    bf16x8 ah[4], al[4], bb[4];
#pragma unroll
    for (int mt = 0; mt < 4; mt++) {
      ah[mt] = *(const bf16x8*)&As[rm + mt * 16 + lm][lk];
      if (!ABF) al[mt] = *(const bf16x8*)&As[rm + mt * 16 + lm][32 + lk];
    }
#pragma unroll
    for (int nt = 0; nt < 4; nt++) bb[nt] = *(const bf16x8*)&Bs[cn + nt * 16 + lm][lk];
#pragma unroll
    for (int mt = 0; mt < 4; mt++)
#pragma unroll
      for (int nt = 0; nt < 4; nt++) {
        acc[mt][nt] = __builtin_amdgcn_mfma_f32_16x16x32_bf16(ah[mt], bb[nt], acc[mt][nt], 0, 0, 0);
        if (!ABF)
          acc[mt][nt] = __builtin_amdgcn_mfma_f32_16x16x32_bf16(al[mt], bb[nt], acc[mt][nt], 0, 0, 0);
      }
    __syncthreads();
  }

  if (SPLIT) {
    short* epi = (short*)&As[0][0];   // 128*64 shorts = 16 KB
    if (wn == 0) {
#pragma unroll
      for (int mt = 0; mt < 4; mt++) {
        int lr = rm + mt * 16 + (lane >> 4) * 4;
#pragma unroll
        for (int r = 0; r < 4; r++) {
          int gr = row0 + lr + r;
          float sc = (SCL && gr < M) ? scl[gr] : 0.f;
#pragma unroll
          for (int nt = 0; nt < 4; nt++)
            epi[(lr + r) * 64 + nt * 16 + lm] = (short)f2bf(acc[mt][nt][r] * sc);
        }
      }
    } else {
#pragma unroll
      for (int mt = 0; mt < 4; mt++) {
        int grb = row0 + rm + mt * 16 + (lane >> 4) * 4;
#pragma unroll
        for (int nt = 0; nt < 4; nt++) {
          int gc = nt * 16 + lm;
          float bv = bias[gc];
#pragma unroll
          for (int r = 0; r < 4; r++) {
            int gr = grb + r;
            if (gr < M) ((float*)Cv2)[(size_t)gr * 64 + gc] = acc[mt][nt][r] + bv;
          }
        }
      }
    }
    __syncthreads();
    int base = tid * 32;
    int row = base >> 6, col = base & 63;
    int gr = row0 + row;
    if (gr < M) {
#pragma unroll
      for (int q = 0; q < 4; q++)
        *(bf16x8*)((short*)Cv + (size_t)gr * 64 + col + q * 8) = *(bf16x8*)&epi[base + q * 8];
    }
  } else if (OBF && WM == 1) {
    short* epi = &Bs[0][0];
    const int NCOL = 64 * WN;
    float bvv[4];
#pragma unroll
    for (int nt = 0; nt < 4; nt++) bvv[nt] = BIAS ? bias[col0 + cn + nt * 16 + lm] : 0.f;
#pragma unroll
    for (int mt = 0; mt < 4; mt++) {
      __syncthreads();
#pragma unroll
      for (int r = 0; r < 4; r++) {
        int gr = row0 + mt * 16 + (lane >> 4) * 4 + r;
        float sc = (SCL && gr < M) ? scl[gr] : 1.f;
#pragma unroll
        for (int nt = 0; nt < 4; nt++) {
          float v = acc[mt][nt][r] + bvv[nt];
          if (RELU) v = (v >= 0.f) ? v : 0.01f * v;
          if (SCL) v *= sc;
          epi[((lane >> 4) * 4 + r) * NCOL + cn + nt * 16 + lm] = (short)f2bf(v);
        }
      }
      __syncthreads();
      const int per = (16 * NCOL) / 256;
      int base = tid * per;
      int lr = base / NCOL, lc = base % NCOL;
      int gr = row0 + mt * 16 + lr;
      if (gr < M) {
#pragma unroll
        for (int q = 0; q < per / 8; q++)
          *(bf16x8*)((short*)Cv + (size_t)gr * NTOT + col0 + lc + q * 8) = *(bf16x8*)&epi[base + q * 8];
      }
    }
  } else {
#pragma unroll
    for (int mt = 0; mt < 4; mt++) {
      int grb = row0 + rm + mt * 16 + (lane >> 4) * 4;
#pragma unroll
      for (int nt = 0; nt < 4; nt++) {
        int gc = col0 + cn + nt * 16 + lm;
        float bv = BIAS ? bias[gc] : 0.f;
#pragma unroll
        for (int r = 0; r < 4; r++) {
          int gr = grb + r;
          if (gr < M) {
            float v = acc[mt][nt][r] + bv;
            if (RELU) v = (v >= 0.f) ? v : 0.01f * v;
            if (SCL) v *= scl[gr];
            if (OBF) ((short*)Cv)[(size_t)gr * NTOT + gc] = (short)f2bf(v);
            else     ((float*)Cv)[(size_t)gr * NTOT + gc] = v;
          }
        }
      }
    }
  }
}

// ------- fused agg256 + layer3 + layer4 (v7) -------
// v6 (WIN: 352->343 us) + gather ILP: grid caps TLP at 3.05 blocks/CU, so raise
// memory-level parallelism instead — each 16-lane quarter interleaves TWO nodes
// (nid, nid+32) with 4-edge unrolls each = 16 bf16x8 loads in flight (2x v6).
// VGPR ~110-125 is free: <=128 keeps 16 waves/CU >= grid demand; launch_bounds
// (256,3) so the allocator doesn't spill chasing unreachable occupancy. Chunk-0
// weight prefetch moved to after the gather (saves 20 VGPR across the fat region;
// still overlaps two barriers + afr reads).

__global__ __launch_bounds__(256, 3) void fused34_k(const short* __restrict__ h2,   // [n][256] bf16
                                                    const int* __restrict__ off, const int* __restrict__ csr,
                                                    const short* __restrict__ W3c,  // [512][256] bf16
                                                    const float* __restrict__ b3,
                                                    const short* __restrict__ W4c,  // [64][512] bf16
                                                    const float* __restrict__ dis,
                                                    short* __restrict__ T4, int M) {
  __shared__ __align__(16) char smem[32768];
  short* Bs  = (short*)smem;                  // [32][264] = 16896 B
  short* Ws4 = (short*)(smem + 16896);        // [64][40]  =  5120 B
  short* Hs  = (short*)(smem + 22016);        // [64][40]  =  5120 B
  const int tid = threadIdx.x;
  const int row0 = blockIdx.x * 64;
  const int w = tid >> 6, lane = tid & 63;
  const int lm = lane & 15, lk = (lane >> 4) * 8;
  const int rquad = (lane >> 4) * 4;
  const int w4row = tid >> 2, w4seg = (tid & 3) * 8;
  const int qtr = lane >> 4, ql = lane & 15;

  // ---- gather 64 z3 rows into Zs[64][256]; 2 nodes per quarter interleaved ----
  short* Zs = (short*)smem;
  for (int pass = 0; pass < 2; pass++) {
    int nidA = pass * 16 + w * 4 + qtr;      // 0..31
    int nidB = nidA + 32;                    // 32..63
    int grA = row0 + nidA, grB = row0 + nidB;
    bool okA = grA < M, okB = grB < M;
    float aA[16], aB[16];
    int eA = 0, e1A = 0, eB = 0, e1B = 0;
    float diA = 0.f, diB = 0.f;
    if (okA) { diA = dis[grA]; eA = off[grA]; e1A = off[grA + 1]; }
    if (okB) { diB = dis[grB]; eB = off[grB]; e1B = off[grB + 1]; }
    {
      bf16x8 sA0 = {0,0,0,0,0,0,0,0}, sA1 = {0,0,0,0,0,0,0,0};
      bf16x8 sB0 = {0,0,0,0,0,0,0,0}, sB1 = {0,0,0,0,0,0,0,0};
      if (okA) {
        const short* base = h2 + (size_t)grA * 256 + ql * 16;
        sA0 = *(const bf16x8*)base; sA1 = *(const bf16x8*)(base + 8);
      }
      if (okB) {
        const short* base = h2 + (size_t)grB * 256 + ql * 16;
        sB0 = *(const bf16x8*)base; sB1 = *(const bf16x8*)(base + 8);
      }
#pragma unroll
      for (int j = 0; j < 8; j++) {
        aA[j] = bf2f((unsigned short)sA0[j]); aA[8 + j] = bf2f((unsigned short)sA1[j]);
        aB[j] = bf2f((unsigned short)sB0[j]); aB[8 + j] = bf2f((unsigned short)sB1[j]);
      }
    }
    // joint main loop: 4 edges per node per iter -> 16 loads in flight
    for (; eA + 4 <= e1A && eB + 4 <= e1B; eA += 4, eB += 4) {
      const short* pA0 = h2 + (size_t)csr[eA]     * 256 + ql * 16;
      const short* pA1 = h2 + (size_t)csr[eA + 1] * 256 + ql * 16;
      const short* pA2 = h2 + (size_t)csr[eA + 2] * 256 + ql * 16;
      const short* pA3 = h2 + (size_t)csr[eA + 3] * 256 + ql * 16;
      const short* pB0 = h2 + (size_t)csr[eB]     * 256 + ql * 16;
      const short* pB1 = h2 + (size_t)csr[eB + 1] * 256 + ql * 16;
      const short* pB2 = h2 + (size_t)csr[eB + 2] * 256 + ql * 16;
      const short* pB3 = h2 + (size_t)csr[eB + 3] * 256 + ql * 16;
      bf16x8 tA00 = *(const bf16x8*)pA0, tA01 = *(const bf16x8*)(pA0 + 8);
      bf16x8 tA10 = *(const bf16x8*)pA1, tA11 = *(const bf16x8*)(pA1 + 8);
      bf16x8 tA20 = *(const bf16x8*)pA2, tA21 = *(const bf16x8*)(pA2 + 8);
      bf16x8 tA30 = *(const bf16x8*)pA3, tA31 = *(const bf16x8*)(pA3 + 8);
      bf16x8 tB00 = *(const bf16x8*)pB0, tB01 = *(const bf16x8*)(pB0 + 8);
      bf16x8 tB10 = *(const bf16x8*)pB1, tB11 = *(const bf16x8*)(pB1 + 8);
      bf16x8 tB20 = *(const bf16x8*)pB2, tB21 = *(const bf16x8*)(pB2 + 8);
      bf16x8 tB30 = *(const bf16x8*)pB3, tB31 = *(const bf16x8*)(pB3 + 8);
#pragma unroll
      for (int j = 0; j < 8; j++) {
        aA[j]     += (bf2f((unsigned short)tA00[j]) + bf2f((unsigned short)tA10[j])) +
                     (bf2f((unsigned short)tA20[j]) + bf2f((unsigned short)tA30[j]));
        aA[8 + j] += (bf2f((unsigned short)tA01[j]) + bf2f((unsigned short)tA11[j])) +
                     (bf2f((unsigned short)tA21[j]) + bf2f((unsigned short)tA31[j]));
        aB[j]     += (bf2f((unsigned short)tB00[j]) + bf2f((unsigned short)tB10[j])) +
                     (bf2f((unsigned short)tB20[j]) + bf2f((unsigned short)tB30[j]));
        aB[8 + j] += (bf2f((unsigned short)tB01[j]) + bf2f((unsigned short)tB11[j])) +
                     (bf2f((unsigned short)tB21[j]) + bf2f((unsigned short)tB31[j]));
      }
    }
    // drain A
    for (; eA + 4 <= e1A; eA += 4) {
      const short* p0 = h2 + (size_t)csr[eA]     * 256 + ql * 16;
      const short* p1 = h2 + (size_t)csr[eA + 1] * 256 + ql * 16;
      const short* p2 = h2 + (size_t)csr[eA + 2] * 256 + ql * 16;
      const short* p3 = h2 + (size_t)csr[eA + 3] * 256 + ql * 16;
      bf16x8 t00 = *(const bf16x8*)p0, t01 = *(const bf16x8*)(p0 + 8);
      bf16x8 t10 = *(const bf16x8*)p1, t11 = *(const bf16x8*)(p1 + 8);
      bf16x8 t20 = *(const bf16x8*)p2, t21 = *(const bf16x8*)(p2 + 8);
      bf16x8 t30 = *(const bf16x8*)p3, t31 = *(const bf16x8*)(p3 + 8);
#pragma unroll
      for (int j = 0; j < 8; j++) {
        aA[j]     += (bf2f((unsigned short)t00[j]) + bf2f((unsigned short)t10[j])) +
                     (bf2f((unsigned short)t20[j]) + bf2f((unsigned short)t30[j]));
        aA[8 + j] += (bf2f((unsigned short)t01[j]) + bf2f((unsigned short)t11[j])) +
                     (bf2f((unsigned short)t21[j]) + bf2f((unsigned short)t31[j]));
      }
    }
    for (; eA < e1A; eA++) {
      const short* p = h2 + (size_t)csr[eA] * 256 + ql * 16;
      bf16x8 t0 = *(const bf16x8*)p, t1 = *(const bf16x8*)(p + 8);
#pragma unroll
      for (int j = 0; j < 8; j++) {
        aA[j] += bf2f((unsigned short)t0[j]);
        aA[8 + j] += bf2f((unsigned short)t1[j]);
      }
    }
    // drain B
    for (; eB + 4 <= e1B; eB += 4) {
      const short* p0 = h2 + (size_t)csr[eB]     * 256 + ql * 16;
      const short* p1 = h2 + (size_t)csr[eB + 1] * 256 + ql * 16;
      const short* p2 = h2 + (size_t)csr[eB + 2] * 256 + ql * 16;
      const short* p3 = h2 + (size_t)csr[eB + 3] * 256 + ql * 16;
      bf16x8 t00 = *(const bf16x8*)p0, t01 = *(const bf16x8*)(p0 + 8);
      bf16x8 t10 = *(const bf16x8*)p1, t11 = *(const bf16x8*)(p1 + 8);
      bf16x8 t20 = *(const bf16x8*)p2, t21 = *(const bf16x8*)(p2 + 8);
      bf16x8 t30 = *(const bf16x8*)p3, t31 = *(const bf16x8*)(p3 + 8);
#pragma unroll
      for (int j = 0; j < 8; j++) {
        aB[j]     += (bf2f((unsigned short)t00[j]) + bf2f((unsigned short)t10[j])) +
                     (bf2f((unsigned short)t20[j]) + bf2f((unsigned short)t30[j]));
        aB[8 + j] += (bf2f((unsigned short)t01[j]) + bf2f((unsigned short)t11[j])) +
                     (bf2f((unsigned short)t21[j]) + bf2f((unsigned short)t31[j]));
      }
    }
    for (; eB < e1B; eB++) {
      const short* p = h2 + (size_t)csr[eB] * 256 + ql * 16;
      bf16x8 t0 = *(const bf16x8*)p, t1 = *(const bf16x8*)(p + 8);
#pragma unroll
      for (int j = 0; j < 8; j++) {
        aB[j] += bf2f((unsigned short)t0[j]);
        aB[8 + j] += bf2f((unsigned short)t1[j]);
      }
    }
    bf16x8 oA0, oA1, oB0, oB1;
#pragma unroll
    for (int j = 0; j < 8; j++) {
      oA0[j] = (short)f2bf(diA * aA[j]);
      oA1[j] = (short)f2bf(diA * aA[8 + j]);
      oB0[j] = (short)f2bf(diB * aB[j]);
      oB1[j] = (short)f2bf(diB * aB[8 + j]);
    }
    *(bf16x8*)&Zs[nidA * 256 + ql * 16] = oA0;
    *(bf16x8*)&Zs[nidA * 256 + ql * 16 + 8] = oA1;
    *(bf16x8*)&Zs[nidB * 256 + ql * 16] = oB0;
    *(bf16x8*)&Zs[nidB * 256 + ql * 16 + 8] = oB1;
  }

  // issue chunk-0 weight loads now: overlap the two barriers + afr reads
  bf16x8 pw3[4];
  bf16x8 pw4;
#pragma unroll
  for (int q = 0; q < 4; q++) pw3[q] = *(const bf16x8*)(W3c + q * 2048 + tid * 8);
  pw4 = *(const bf16x8*)(W4c + (size_t)w4row * 512 + w4seg);
  __syncthreads();

  // A fragments from Zs (one-time 16-way-conflicted read; negligible)
  bf16x8 afr[8];
  {
    int lr = w * 16 + lm;
#pragma unroll
    for (int kc = 0; kc < 8; kc++)
      afr[kc] = *(const bf16x8*)&Zs[lr * 256 + kc * 32 + lk];
  }
  __syncthreads();

  // write chunk 0
#pragma unroll
  for (int q = 0; q < 4; q++) {
    int flat = q * 2048 + tid * 8;
    *(bf16x8*)&Bs[(flat >> 8) * 264 + (flat & 255)] = pw3[q];
  }
  *(bf16x8*)&Ws4[w4row * 40 + w4seg] = pw4;
  __syncthreads();

  f32x4 t4acc[4];
#pragma unroll
  for (int nt = 0; nt < 4; nt++)
#pragma unroll
    for (int r = 0; r < 4; r++) t4acc[nt][r] = 0.f;

  for (int c = 0; c < 16; c++) {
    if (c < 15) {
#pragma unroll
      for (int q = 0; q < 4; q++) {
        int flat = q * 2048 + tid * 8;
        pw3[q] = *(const bf16x8*)(W3c + (size_t)(c + 1) * 8192 + flat);
      }
      pw4 = *(const bf16x8*)(W4c + (size_t)w4row * 512 + (c + 1) * 32 + w4seg);
    }

    f32x4 acc1[2];
#pragma unroll
    for (int nt = 0; nt < 2; nt++)
#pragma unroll
      for (int r = 0; r < 4; r++) acc1[nt][r] = 0.f;
#pragma unroll
    for (int k0 = 0; k0 < 8; k0++) {
      bf16x8 bb[2];
#pragma unroll
      for (int nt = 0; nt < 2; nt++) bb[nt] = *(const bf16x8*)&Bs[(nt * 16 + lm) * 264 + k0 * 32 + lk];
#pragma unroll
      for (int nt = 0; nt < 2; nt++)
        acc1[nt] = __builtin_amdgcn_mfma_f32_16x16x32_bf16(afr[k0], bb[nt], acc1[nt], 0, 0, 0);
    }
#pragma unroll
    for (int nt = 0; nt < 2; nt++) {
      float bv = b3[c * 32 + nt * 16 + lm];
#pragma unroll
      for (int r = 0; r < 4; r++) {
        float v = acc1[nt][r] + bv;
        v = (v >= 0.f) ? v : 0.01f * v;
        Hs[(w * 16 + rquad + r) * 40 + nt * 16 + lm] = (short)f2bf(v);
      }
    }
    {
      bf16x8 ah2 = *(const bf16x8*)&Hs[(w * 16 + lm) * 40 + lk];
      bf16x8 bb2[4];
#pragma unroll
      for (int nt = 0; nt < 4; nt++) bb2[nt] = *(const bf16x8*)&Ws4[(nt * 16 + lm) * 40 + lk];
#pragma unroll
      for (int nt = 0; nt < 4; nt++)
        t4acc[nt] = __builtin_amdgcn_mfma_f32_16x16x32_bf16(ah2, bb2[nt], t4acc[nt], 0, 0, 0);
    }
    __syncthreads();                         // all consumers of chunk c done
    if (c < 15) {
#pragma unroll
      for (int q = 0; q < 4; q++) {
        int flat = q * 2048 + tid * 8;
        *(bf16x8*)&Bs[(flat >> 8) * 264 + (flat & 255)] = pw3[q];
      }
      *(bf16x8*)&Ws4[w4row * 40 + w4seg] = pw4;
    }
    __syncthreads();                         // chunk c+1 visible
  }

  short* epi = (short*)smem;                 // 64*64 shorts = 8 KB
#pragma unroll
  for (int r = 0; r < 4; r++) {
    int lr = w * 16 + rquad + r;
    int gr = row0 + lr;
    float sc = (gr < M) ? dis[gr] : 0.f;
#pragma unroll
    for (int nt = 0; nt < 4; nt++)
      epi[lr * 64 + nt * 16 + lm] = (short)f2bf(t4acc[nt][r] * sc);
  }
  __syncthreads();
  {
    int base = tid * 16;
    int row = base >> 6, col = base & 63;
    int gr = row0 + row;
    if (gr < M) {
      *(bf16x8*)(T4 + (size_t)gr * 64 + col)     = *(bf16x8*)&epi[base];
      *(bf16x8*)(T4 + (size_t)gr * 64 + col + 8) = *(bf16x8*)&epi[base + 8];
    }
  }
}

// ------- Aggregation (dis-free; rows pre-scaled). Quad-node: 4 nodes/wave. -------
// Lane quarter q -> node 4w+q; each lane covers 4 features (8B, uint2).

template<int BR, int OSCL>
__global__ __launch_bounds__(256) void aggb64_k(const short* __restrict__ T, const float* __restrict__ dis,
                                                const int* __restrict__ off, const int* __restrict__ csr,
                                                const float* __restrict__ bias, short* __restrict__ Out, int n) {
  int wv = (blockIdx.x * 256 + threadIdx.x) >> 6;
  int lane = threadIdx.x & 63;
  int qtr = lane >> 4, ql = lane & 15;
  int wid = wv * 4 + qtr;
  if (wid >= n) return;
  float di = dis[wid];
  int e0 = off[wid], e1 = off[wid + 1];
  const uint2* Tw = (const uint2*)T;   // 4 bf16 per uint2; row = 16 uint2
  uint2 su = Tw[(size_t)wid * 16 + ql];
  float a0 = bflo(su.x), a1 = bfhi(su.x), a2 = bflo(su.y), a3 = bfhi(su.y);
  int e = e0;
  for (; e + 8 <= e1; e += 8) {
    uint2 u0 = Tw[(size_t)csr[e]     * 16 + ql];
    uint2 u1 = Tw[(size_t)csr[e + 1] * 16 + ql];
    uint2 u2 = Tw[(size_t)csr[e + 2] * 16 + ql];
    uint2 u3 = Tw[(size_t)csr[e + 3] * 16 + ql];
    uint2 u4 = Tw[(size_t)csr[e + 4] * 16 + ql];
    uint2 u5 = Tw[(size_t)csr[e + 5] * 16 + ql];
    uint2 u6 = Tw[(size_t)csr[e + 6] * 16 + ql];
    uint2 u7 = Tw[(size_t)csr[e + 7] * 16 + ql];
    a0 += ((bflo(u0.x) + bflo(u1.x)) + (bflo(u2.x) + bflo(u3.x))) +
          ((bflo(u4.x) + bflo(u5.x)) + (bflo(u6.x) + bflo(u7.x)));
    a1 += ((bfhi(u0.x) + bfhi(u1.x)) + (bfhi(u2.x) + bfhi(u3.x))) +
          ((bfhi(u4.x) + bfhi(u5.x)) + (bfhi(u6.x) + bfhi(u7.x)));
    a2 += ((bflo(u0.y) + bflo(u1.y)) + (bflo(u2.y) + bflo(u3.y))) +
          ((bflo(u4.y) + bflo(u5.y)) + (bflo(u6.y) + bflo(u7.y)));
    a3 += ((bfhi(u0.y) + bfhi(u1.y)) + (bfhi(u2.y) + bfhi(u3.y))) +
          ((bfhi(u4.y) + bfhi(u5.y)) + (bfhi(u6.y) + bfhi(u7.y)));
  }
  for (; e + 4 <= e1; e += 4) {
    uint2 u0 = Tw[(size_t)csr[e]     * 16 + ql];
    uint2 u1 = Tw[(size_t)csr[e + 1] * 16 + ql];
    uint2 u2 = Tw[(size_t)csr[e + 2] * 16 + ql];
    uint2 u3 = Tw[(size_t)csr[e + 3] * 16 + ql];
    a0 += (bflo(u0.x) + bflo(u1.x)) + (bflo(u2.x) + bflo(u3.x));
    a1 += (bfhi(u0.x) + bfhi(u1.x)) + (bfhi(u2.x) + bfhi(u3.x));
    a2 += (bflo(u0.y) + bflo(u1.y)) + (bflo(u2.y) + bflo(u3.y));
    a3 += (bfhi(u0.y) + bfhi(u1.y)) + (bfhi(u2.y) + bfhi(u3.y));
  }
  for (; e < e1; e++) {
    uint2 u = Tw[(size_t)csr[e] * 16 + ql];
    a0 += bflo(u.x); a1 += bfhi(u.x); a2 += bflo(u.y); a3 += bfhi(u.y);
  }
  float v0 = di * a0, v1 = di * a1, v2 = di * a2, v3 = di * a3;
  if (BR) {
    v0 += bias[ql * 4];     v1 += bias[ql * 4 + 1];
    v2 += bias[ql * 4 + 2]; v3 += bias[ql * 4 + 3];
    v0 = (v0 >= 0.f) ? v0 : 0.01f * v0;
    v1 = (v1 >= 0.f) ? v1 : 0.01f * v1;
    v2 = (v2 >= 0.f) ? v2 : 0.01f * v2;
    v3 = (v3 >= 0.f) ? v3 : 0.01f * v3;
  }
  if (OSCL) { v0 *= di; v1 *= di; v2 *= di; v3 *= di; }
  uint2 o;
  o.x = (unsigned)f2bf(v0) | ((unsigned)f2bf(v1) << 16);
  o.y = (unsigned)f2bf(v2) | ((unsigned)f2bf(v3) << 16);
  ((uint2*)Out)[(size_t)wid * 16 + ql] = o;
}

// layer-4 tail (quad-node): hn = LN( leaky(di*sum(t4b) + b4) + resid )
// 16-lane LN reduction per quarter (shfl offsets 8/4/2/1 stay within the quarter).
__global__ __launch_bounds__(256) void agg64_ln_k(const short* __restrict__ T, const float* __restrict__ dis,
                                                  const int* __restrict__ off, const int* __restrict__ csr,
                                                  const float* __restrict__ bias, const float* __restrict__ resid,
                                                  const float* __restrict__ g, const float* __restrict__ b,
                                                  float* __restrict__ outh, int n) {
  int wv = (blockIdx.x * 256 + threadIdx.x) >> 6;
  int lane = threadIdx.x & 63;
  int qtr = lane >> 4, ql = lane & 15;
  int wid = wv * 4 + qtr;
  if (wid >= n) return;
  float di = dis[wid];
  int e0 = off[wid], e1 = off[wid + 1];
  const uint2* Tw = (const uint2*)T;
  uint2 su = Tw[(size_t)wid * 16 + ql];
  float a0 = bflo(su.x), a1 = bfhi(su.x), a2 = bflo(su.y), a3 = bfhi(su.y);
  int e = e0;
  for (; e + 8 <= e1; e += 8) {
    uint2 u0 = Tw[(size_t)csr[e]     * 16 + ql];
    uint2 u1 = Tw[(size_t)csr[e + 1] * 16 + ql];
    uint2 u2 = Tw[(size_t)csr[e + 2] * 16 + ql];
    uint2 u3 = Tw[(size_t)csr[e + 3] * 16 + ql];
    uint2 u4 = Tw[(size_t)csr[e + 4] * 16 + ql];
    uint2 u5 = Tw[(size_t)csr[e + 5] * 16 + ql];
    uint2 u6 = Tw[(size_t)csr[e + 6] * 16 + ql];
    uint2 u7 = Tw[(size_t)csr[e + 7] * 16 + ql];
    a0 += ((bflo(u0.x) + bflo(u1.x)) + (bflo(u2.x) + bflo(u3.x))) +
          ((bflo(u4.x) + bflo(u5.x)) + (bflo(u6.x) + bflo(u7.x)));
    a1 += ((bfhi(u0.x) + bfhi(u1.x)) + (bfhi(u2.x) + bfhi(u3.x))) +
          ((bfhi(u4.x) + bfhi(u5.x)) + (bfhi(u6.x) + bfhi(u7.x)));
    a2 += ((bflo(u0.y) + bflo(u1.y)) + (bflo(u2.y) + bflo(u3.y))) +
          ((bflo(u4.y) + bflo(u5.y)) + (bflo(u6.y) + bflo(u7.y)));
    a3 += ((bfhi(u0.y) + bfhi(u1.y)) + (bfhi(u2.y) + bfhi(u3.y))) +
          ((bfhi(u4.y) + bfhi(u5.y)) + (bfhi(u6.y) + bfhi(u7.y)));
  }
  for (; e + 4 <= e1; e += 4) {
    uint2 u0 = Tw[(size_t)csr[e]     * 16 + ql];
    uint2 u1 = Tw[(size_t)csr[e + 1] * 16 + ql];
    uint2 u2 = Tw[(size_t)csr[e + 2] * 16 + ql];
    uint2 u3 = Tw[(size_t)csr[e + 3] * 16 + ql];
    a0 += (bflo(u0.x) + bflo(u1.x)) + (bflo(u2.x) + bflo(u3.x));
    a1 += (bfhi(u0.x) + bfhi(u1.x)) + (bfhi(u2.x) + bfhi(u3.x));
    a2 += (bflo(u0.y) + bflo(u1.y)) + (bflo(u2.y) + bflo(u3.y));
    a3 += (bfhi(u0.y) + bfhi(u1.y)) + (bfhi(u2.y) + bfhi(u3.y));
  }
  for (; e < e1; e++) {
    uint2 u = Tw[(size_t)csr[e] * 16 + ql];
    a0 += bflo(u.x); a1 += bfhi(u.x); a2 += bflo(u.y); a3 += bfhi(u.y);
  }
  float4 rv = ((const float4*)resid)[(size_t)wid * 16 + ql];
  float v0 = di * a0 + bias[ql * 4];
  float v1 = di * a1 + bias[ql * 4 + 1];
  float v2 = di * a2 + bias[ql * 4 + 2];
  float v3 = di * a3 + bias[ql * 4 + 3];
  v0 = (v0 >= 0.f) ? v0 : 0.01f * v0;
  v1 = (v1 >= 0.f) ? v1 : 0.01f * v1;
  v2 = (v2 >= 0.f) ? v2 : 0.01f * v2;
  v3 = (v3 >= 0.f) ? v3 : 0.01f * v3;
  v0 += rv.x; v1 += rv.y; v2 += rv.z; v3 += rv.w;
  float s = (v0 + v1) + (v2 + v3);
  float ss = (v0 * v0 + v1 * v1) + (v2 * v2 + v3 * v3);
#pragma unroll
  for (int o = 8; o > 0; o >>= 1) {
    s += __shfl_xor(s, o);
    ss += __shfl_xor(ss, o);
  }
  float m = s * (1.f / 64.f);
  float var = ss * (1.f / 64.f) - m * m;
  float rs = rsqrtf(var + 1e-5f);
  float4 o4;
  o4.x = (v0 - m) * rs * g[ql * 4]     + b[ql * 4];
  o4.y = (v1 - m) * rs * g[ql * 4 + 1] + b[ql * 4 + 1];
  o4.z = (v2 - m) * rs * g[ql * 4 + 2] + b[ql * 4 + 2];
  o4.w = (v3 - m) * rs * g[ql * 4 + 3] + b[ql * 4 + 3];
  ((float4*)outh)[(size_t)wid * 16 + ql] = o4;
}

// ---------------- per-graph max pool + final MLP (fused, one block per graph) ----------------

__global__ __launch_bounds__(256) void pool_mlp_k(const float* __restrict__ hn,
                                                  const float* __restrict__ fc1W, const float* __restrict__ fc1b,
                                                  const float* __restrict__ fng, const float* __restrict__ fnb,
                                                  const float* __restrict__ fc2W, const float* __restrict__ fc2b,
                                                  float* __restrict__ out, int n) {
  const int G = 64;
  int g = blockIdx.x;
  int f = threadIdx.x & 63, c = threadIdx.x >> 6;
  long long s0 = ((long long)g * n + G - 1) / G;
  long long e0 = ((long long)(g + 1) * n + G - 1) / G;
  float m = -INFINITY;
  for (long long i = s0 + c; i < e0; i += 4) m = fmaxf(m, hn[(size_t)i * 64 + f]);
  __shared__ float red[4][64];
  __shared__ float ps[64], qs[64];
  red[c][f] = m;
  __syncthreads();
  if (c == 0) ps[f] = fmaxf(fmaxf(red[0][f], red[1][f]), fmaxf(red[2][f], red[3][f]));
  __syncthreads();
  if (threadIdx.x < 64) {
    int lane = threadIdx.x;
    float q = fc1b[lane];
#pragma unroll 8
    for (int k = 0; k < 64; k++) q = fmaf(ps[k], fc1W[k * 64 + lane], q);
    float s = q, ss = q * q;
#pragma unroll
    for (int o = 32; o > 0; o >>= 1) {
      s += __shfl_xor(s, o);
      ss += __shfl_xor(ss, o);
    }
    float mm = s * (1.f / 64.f);
    float var = ss * (1.f / 64.f) - mm * mm;
    float y = (q - mm) * rsqrtf(var + 1e-5f) * fng[lane] + fnb[lane];
    y = (y >= 0.f) ? y : 0.01f * y;
    qs[lane] = y;
    __builtin_amdgcn_wave_barrier();
    if (lane < 16) {
      float o = fc2b[lane];
#pragma unroll 8
      for (int k = 0; k < 64; k++) o = fmaf(qs[k], fc2W[k * 16 + lane], o);
      out[g * 16 + lane] = o;
    }
  }
}

// ---------------- launch ----------------

extern "C" void kernel_launch(void* const* d_in, const int* in_sizes, int n_in,
                              void* d_out, int out_size, void* d_ws, size_t ws_size,
                              hipStream_t stream) {
  const float* x   = (const float*)d_in[0];
  const int*   ei  = (const int*)d_in[1];
  const float* W1  = (const float*)d_in[3];
  const float* b1  = (const float*)d_in[4];
  const float* W2  = (const float*)d_in[5];
  const float* b2  = (const float*)d_in[6];
  const float* W3  = (const float*)d_in[7];
  const float* b3  = (const float*)d_in[8];
  const float* W4  = (const float*)d_in[9];
  const float* b4  = (const float*)d_in[10];
  const float* Wr  = (const float*)d_in[11];
  const float* br  = (const float*)d_in[12];
  const float* lng = (const float*)d_in[13];
  const float* lnb = (const float*)d_in[14];
  const float* f1W = (const float*)d_in[15];
  const float* f1b = (const float*)d_in[16];
  const float* fng = (const float*)d_in[17];
  const float* fnb = (const float*)d_in[18];
  const float* f2W = (const float*)d_in[19];
  const float* f2b = (const float*)d_in[20];

  int n = in_sizes[0] / 128;   // 50000
  int e = in_sizes[1] / 2;     // 400000
  const int* src = ei;
  const int* dst = ei + e;

  float* arena = (float*)d_ws;
  float* resid = arena;                              // [0, 64n)
  short* h2b   = (short*)(arena + (size_t)64 * n);   // [64n, 192n) : n x 256 bf16, live until fused34 done
  short* t4b   = (short*)(arena + (size_t)192 * n);  // [192n, 224n): n x 64 bf16
  float* hn    = arena + (size_t)224 * n;            // [224n, 288n): n x 64 f32
  short* t1b   = (short*)(arena + (size_t)320 * n);
  short* h1b   = (short*)(arena + (size_t)352 * n);
  short* z2b   = (short*)(arena + (size_t)384 * n);
  float* dis   = arena + (size_t)448 * n;  // n
  int* cnt    = (int*)(dis + n);           // n
  int* off    = cnt + n;                   // n+1
  int* cursor = off + n + 1;               // n
  int* csr    = cursor + n;                // e
  int* bsum   = csr + e;                   // 256
  int* bpre   = bsum + 256;                // 256
  float* pool = (float*)(bpre + 256);      // layout keep
  size_t wq = (((size_t)(pool + 4096)) + 15) & ~(size_t)15;
  short* wc1 = (short*)wq;                 // 64 x 128   (wc1||wcR = fused 128 x 128)
  short* wcR = wc1 + 8192;                 // 64 x 128
  short* wc2 = wcR + 8192;                 // 256 x 64
  short* wc3 = wc2 + 16384;                // 512 x 256
  short* wc4 = wc3 + 131072;               // 64 x 512
  size_t need = ((char*)(wc4 + 32768) - (char*)d_ws) + 64;
  if (ws_size < need) return;

  int nb_n = (n + 255) / 256;        // 196
  int nb_e = (e + 255) / 256;
  int nb_w4 = ((n + 3) / 4 + 3) / 4; // four nodes per wave
  int g_wide = (n + 63) / 64;        // 782
  int g_fused = (n + 127) / 128;     // 391

  // weights -> bf16 [N][K]
  wconv_k<<<960, 256, 0, stream>>>(W1, Wr, W2, W3, W4, wc1, wcR, wc2, wc3, wc4);

  // degree + CSR (hierarchical scan; dis fused into scan_c)
  hipMemsetAsync(cnt, 0, (size_t)n * sizeof(int), stream);
  count_k<<<nb_e, 256, 0, stream>>>(dst, cnt, e);
  scan_a<<<nb_n, 256, 0, stream>>>(cnt, bsum, n);
  scan_b<<<1, 256, 0, stream>>>(bsum, bpre, off + n, nb_n);
  scan_c<<<nb_n, 256, 0, stream>>>(cnt, bpre, off, cursor, dis, n);
  scatter_k<<<nb_e, 256, 0, stream>>>(src, dst, cursor, csr, e);

  // fused L1 + residual: t1b = bf16(dis*(x@W1)); resid = x@Wr + br
  mgemm<128, 128, 2, 2, 1, 0, 0, 0, 1, 1, 4><<<dim3(g_fused, 1), 256, 0, stream>>>(x, wc1, br, t1b, resid, dis, n);
  // h1b = bf16( dis * leaky(di*sum(t1) + b1) )
  aggb64_k<1, 1><<<nb_w4, 256, 0, stream>>>(t1b, dis, off, csr, b1, h1b, n);
  // z2b = bf16( di * sum(h1) )
  aggb64_k<0, 0><<<nb_w4, 256, 0, stream>>>(h1b, dis, off, csr, nullptr, z2b, n);
  // h2b = bf16( dis * leaky(z2@W2 + b2) )
  mgemm<64, 256, 1, 4, 1, 1, 1, 1, 0, 1, 5><<<dim3(g_wide, 1), 256, 0, stream>>>(z2b, wc2, b2, h2b, nullptr, dis, n);
  // t4b = bf16( dis * (leaky(agg256(h2b)@W3+b3) @ W4) )   (agg256 + L3 + L4 fused, v7)
  fused34_k<<<g_wide, 256, 0, stream>>>(h2b, off, csr, wc3, b3, wc4, dis, t4b, n);
  // hn = LN( leaky(di*sum(t4b) + b4) + resid )   (quad-node)
  agg64_ln_k<<<nb_w4, 256, 0, stream>>>(t4b, dis, off, csr, b4, resid, lng, lnb, hn, n);
  // pool + MLP fused
  pool_mlp_k<<<64, 256, 0, stream>>>(hn, f1W, f1b, fng, fnb, f2W, f2b, (float*)d_out, n);
}

// Round 9
// 338.416 us; speedup vs baseline: 1.0430x; 1.0430x over previous
//
#include <hip/hip_runtime.h>
#include <hip/hip_bf16.h>
#include <math.h>

typedef short bf16x8 __attribute__((ext_vector_type(8)));
typedef short bf16x4 __attribute__((ext_vector_type(4)));
typedef float f32x4 __attribute__((ext_vector_type(4)));

__device__ inline unsigned short f2bf(float f) {
  unsigned u = __float_as_uint(f);
  u += 0x7FFF + ((u >> 16) & 1);           // RNE
  return (unsigned short)(u >> 16);
}
__device__ inline float bf2f(unsigned short h) {
  return __uint_as_float(((unsigned)h) << 16);
}
__device__ inline float bflo(unsigned u) { return __uint_as_float(u << 16); }
__device__ inline float bfhi(unsigned u) { return __uint_as_float(u & 0xffff0000u); }

// ---------------- CSR build ----------------

__global__ __launch_bounds__(256) void count_k(const int* __restrict__ dst, int* __restrict__ cnt, int e) {
  int i = blockIdx.x * 256 + threadIdx.x;
  if (i < e) atomicAdd(&cnt[dst[i]], 1);
}

__global__ __launch_bounds__(256) void scan_a(const int* __restrict__ cnt, int* __restrict__ bsum, int n) {
  int i = blockIdx.x * 256 + threadIdx.x;
  int v = (i < n) ? cnt[i] : 0;
#pragma unroll
  for (int o = 32; o > 0; o >>= 1) v += __shfl_xor(v, o);
  __shared__ int ws[4];
  if ((threadIdx.x & 63) == 0) ws[threadIdx.x >> 6] = v;
  __syncthreads();
  if (threadIdx.x == 0) bsum[blockIdx.x] = ws[0] + ws[1] + ws[2] + ws[3];
}

__global__ __launch_bounds__(256) void scan_b(const int* __restrict__ bsum, int* __restrict__ bpre,
                                              int* __restrict__ off_n, int nb) {
  __shared__ int s[256];
  int t = threadIdx.x;
  int v = (t < nb) ? bsum[t] : 0;
  s[t] = v;
  __syncthreads();
  for (int o = 1; o < 256; o <<= 1) {
    int u = (t >= o) ? s[t - o] : 0;
    __syncthreads();
    s[t] += u;
    __syncthreads();
  }
  if (t < nb) bpre[t] = s[t] - v;
  if (t == 255) off_n[0] = s[255];
}

// scan_c also computes dis = rsqrt(cnt+1)
__global__ __launch_bounds__(256) void scan_c(const int* __restrict__ cnt, const int* __restrict__ bpre,
                                              int* __restrict__ off, int* __restrict__ cursor,
                                              float* __restrict__ dis, int n) {
  __shared__ int s[256];
  int i = blockIdx.x * 256 + threadIdx.x;
  int t = threadIdx.x;
  int v = (i < n) ? cnt[i] : 0;
  s[t] = v;
  __syncthreads();
  for (int o = 1; o < 256; o <<= 1) {
    int u = (t >= o) ? s[t - o] : 0;
    __syncthreads();
    s[t] += u;
    __syncthreads();
  }
  if (i < n) {
    int ov = bpre[blockIdx.x] + s[t] - v;
    off[i] = ov;
    cursor[i] = ov;
    dis[i] = rsqrtf((float)v + 1.0f);
  }
}

__global__ __launch_bounds__(256) void scatter_k(const int* __restrict__ src, const int* __restrict__ dst,
                                                 int* __restrict__ cursor, int* __restrict__ csr, int e) {
  int i = blockIdx.x * 256 + threadIdx.x;
  if (i < e) {
    int p = atomicAdd(&cursor[dst[i]], 1);
    csr[p] = src[i];
  }
}

// ------- weight convert: W[K][N] fp32 -> Wc[N][K] bf16 -------

__global__ __launch_bounds__(256) void wconv_k(const float* __restrict__ W1, const float* __restrict__ Wr,
                                               const float* __restrict__ W2, const float* __restrict__ W3,
                                               const float* __restrict__ W4,
                                               short* __restrict__ o1, short* __restrict__ oR,
                                               short* __restrict__ o2, short* __restrict__ o3,
                                               short* __restrict__ o4) {
  int b = blockIdx.x;  // 960 rows total
  const float* W; short* O; int K, N, nr;
  if (b < 64)       { W = W1; O = o1; K = 128; N = 64;  nr = b; }
  else if (b < 128) { W = Wr; O = oR; K = 128; N = 64;  nr = b - 64; }
  else if (b < 384) { W = W2; O = o2; K = 64;  N = 256; nr = b - 128; }
  else if (b < 896) { W = W3; O = o3; K = 256; N = 512; nr = b - 384; }
  else              { W = W4; O = o4; K = 512; N = 64;  nr = b - 896; }
  for (int k = threadIdx.x; k < K; k += 256)
    O[(size_t)nr * K + k] = (short)f2bf(W[(size_t)k * N + nr]);
}

// ------- MFMA GEMM (generic): C[M,NTOT] = A[M,KT] @ Wc[NTOT,KT](bf16) -------

template<int KT, int NTOT, int WM, int WN, int BIAS, int RELU, int ABF, int OBF, int SPLIT, int SCL, int BLK>
__global__ __launch_bounds__(256, BLK) void mgemm(const void* __restrict__ Av,
                                                  const short* __restrict__ Wc,
                                                  const float* __restrict__ bias,
                                                  void* __restrict__ Cv, void* __restrict__ Cv2,
                                                  const float* __restrict__ scl, int M) {
  __shared__ short As[64 * WM][ABF ? 40 : 72];
  __shared__ short Bs[64 * WN][40];
  const int tid = threadIdx.x;
  const int row0 = blockIdx.x * (64 * WM);
  const int col0 = blockIdx.y * (64 * WN);
  const int w = tid >> 6, lane = tid & 63;
  const int wm = w / WN, wn = w % WN;
  const int rm = wm * 64, cn = wn * 64;
  const int lm = lane & 15, lk = (lane >> 4) * 8;

  f32x4 acc[4][4];
#pragma unroll
  for (int i = 0; i < 4; i++)
#pragma unroll
    for (int j = 0; j < 4; j++)
#pragma unroll
      for (int r = 0; r < 4; r++) acc[i][j][r] = 0.f;

  for (int k0 = 0; k0 < KT; k0 += 32) {
#pragma unroll
    for (int p = 0; p < WM; p++) {
      int r = (tid >> 2) + p * 64;
      int kseg = (tid & 3) * 8;
      int gr = row0 + r;
      if (ABF) {
        bf16x8 v = {0, 0, 0, 0, 0, 0, 0, 0};
        if (gr < M) v = *(const bf16x8*)((const short*)Av + (size_t)gr * KT + k0 + kseg);
        *(bf16x8*)&As[r][kseg] = v;
      } else {
        float4 v0 = {0.f, 0.f, 0.f, 0.f}, v1 = {0.f, 0.f, 0.f, 0.f};
        if (gr < M) {
          const float* ap = (const float*)Av + (size_t)gr * KT + k0 + kseg;
          v0 = *(const float4*)ap;
          v1 = *(const float4*)(ap + 4);
        }
        float vv[8] = {v0.x, v0.y, v0.z, v0.w, v1.x, v1.y, v1.z, v1.w};
        bf16x8 hv, lv;
#pragma unroll
        for (int j = 0; j < 8; j++) {
          unsigned short h = f2bf(vv[j]);
          hv[j] = (short)h;
          lv[j] = (short)f2bf(vv[j] - bf2f(h));
        }
        *(bf16x8*)&As[r][kseg] = hv;
        *(bf16x8*)&As[r][32 + kseg] = lv;
      }
    }
#pragma unroll
    for (int p = 0; p < WN; p++) {
      int nr = (tid >> 2) + p * 64;
      int seg = (tid & 3) * 8;
      *(bf16x8*)&Bs[nr][seg] = *(const bf16x8*)(Wc + (size_t)(col0 + nr) * KT + k0 + seg);
    }
    __syncthreads();

    bf16x8 ah[4], al[4], bb[4];
#pragma unroll
    for (int mt = 0; mt < 4; mt++) {
      ah[mt] = *(const bf16x8*)&As[rm + mt * 16 + lm][lk];
      if (!ABF) al[mt] = *(const bf16x8*)&As[rm + mt * 16 + lm][32 + lk];
    }
#pragma unroll
    for (int nt = 0; nt < 4; nt++) bb[nt] = *(const bf16x8*)&Bs[cn + nt * 16 + lm][lk];
#pragma unroll
    for (int mt = 0; mt < 4; mt++)
#pragma unroll
      for (int nt = 0; nt < 4; nt++) {
        acc[mt][nt] = __builtin_amdgcn_mfma_f32_16x16x32_bf16(ah[mt], bb[nt], acc[mt][nt], 0, 0, 0);
        if (!ABF)
          acc[mt][nt] = __builtin_amdgcn_mfma_f32_16x16x32_bf16(al[mt], bb[nt], acc[mt][nt], 0, 0, 0);
      }
    __syncthreads();
  }

  if (SPLIT) {
    short* epi = (short*)&As[0][0];   // 128*64 shorts = 16 KB
    if (wn == 0) {
#pragma unroll
      for (int mt = 0; mt < 4; mt++) {
        int lr = rm + mt * 16 + (lane >> 4) * 4;
#pragma unroll
        for (int r = 0; r < 4; r++) {
          int gr = row0 + lr + r;
          float sc = (SCL && gr < M) ? scl[gr] : 0.f;
#pragma unroll
          for (int nt = 0; nt < 4; nt++)
            epi[(lr + r) * 64 + nt * 16 + lm] = (short)f2bf(acc[mt][nt][r] * sc);
        }
      }
    } else {
#pragma unroll
      for (int mt = 0; mt < 4; mt++) {
        int grb = row0 + rm + mt * 16 + (lane >> 4) * 4;
#pragma unroll
        for (int nt = 0; nt < 4; nt++) {
          int gc = nt * 16 + lm;
          float bv = bias[gc];
#pragma unroll
          for (int r = 0; r < 4; r++) {
            int gr = grb + r;
            if (gr < M) ((float*)Cv2)[(size_t)gr * 64 + gc] = acc[mt][nt][r] + bv;
          }
        }
      }
    }
    __syncthreads();
    int base = tid * 32;
    int row = base >> 6, col = base & 63;
    int gr = row0 + row;
    if (gr < M) {
#pragma unroll
      for (int q = 0; q < 4; q++)
        *(bf16x8*)((short*)Cv + (size_t)gr * 64 + col + q * 8) = *(bf16x8*)&epi[base + q * 8];
    }
  } else if (OBF && WM == 1) {
    short* epi = &Bs[0][0];
    const int NCOL = 64 * WN;
    float bvv[4];
#pragma unroll
    for (int nt = 0; nt < 4; nt++) bvv[nt] = BIAS ? bias[col0 + cn + nt * 16 + lm] : 0.f;
#pragma unroll
    for (int mt = 0; mt < 4; mt++) {
      __syncthreads();
#pragma unroll
      for (int r = 0; r < 4; r++) {
        int gr = row0 + mt * 16 + (lane >> 4) * 4 + r;
        float sc = (SCL && gr < M) ? scl[gr] : 1.f;
#pragma unroll
        for (int nt = 0; nt < 4; nt++) {
          float v = acc[mt][nt][r] + bvv[nt];
          if (RELU) v = (v >= 0.f) ? v : 0.01f * v;
          if (SCL) v *= sc;
          epi[((lane >> 4) * 4 + r) * NCOL + cn + nt * 16 + lm] = (short)f2bf(v);
        }
      }
      __syncthreads();
      const int per = (16 * NCOL) / 256;
      int base = tid * per;
      int lr = base / NCOL, lc = base % NCOL;
      int gr = row0 + mt * 16 + lr;
      if (gr < M) {
#pragma unroll
        for (int q = 0; q < per / 8; q++)
          *(bf16x8*)((short*)Cv + (size_t)gr * NTOT + col0 + lc + q * 8) = *(bf16x8*)&epi[base + q * 8];
      }
    }
  } else {
#pragma unroll
    for (int mt = 0; mt < 4; mt++) {
      int grb = row0 + rm + mt * 16 + (lane >> 4) * 4;
#pragma unroll
      for (int nt = 0; nt < 4; nt++) {
        int gc = col0 + cn + nt * 16 + lm;
        float bv = BIAS ? bias[gc] : 0.f;
#pragma unroll
        for (int r = 0; r < 4; r++) {
          int gr = grb + r;
          if (gr < M) {
            float v = acc[mt][nt][r] + bv;
            if (RELU) v = (v >= 0.f) ? v : 0.01f * v;
            if (SCL) v *= scl[gr];
            if (OBF) ((short*)Cv)[(size_t)gr * NTOT + gc] = (short)f2bf(v);
            else     ((float*)Cv)[(size_t)gr * NTOT + gc] = v;
          }
        }
      }
    }
  }
}

// ------- fused agg256 + layer3 + layer4 (v8) -------
// v6 (proven 342.6 us) with ONE change: the gather main loop is 8-edge unrolled
// (16 bf16x8 loads in flight per quarter, single induction var) instead of 4-edge.
// This is v7's MLP goal without its min(degA,degB) pathology (v7's joint dual-node
// loop pushed most edges into sequential drains -> regression). launch_bounds
// (256,3): grid supplies ~3 blocks/CU anyway; gives the allocator room to batch
// the 16 loads (v7's VGPR=72 showed the compiler serialized under pressure).

__global__ __launch_bounds__(256, 3) void fused34_k(const short* __restrict__ h2,   // [n][256] bf16
                                                    const int* __restrict__ off, const int* __restrict__ csr,
                                                    const short* __restrict__ W3c,  // [512][256] bf16
                                                    const float* __restrict__ b3,
                                                    const short* __restrict__ W4c,  // [64][512] bf16
                                                    const float* __restrict__ dis,
                                                    short* __restrict__ T4, int M) {
  __shared__ __align__(16) char smem[32768];
  short* Bs  = (short*)smem;                  // [32][264] = 16896 B
  short* Ws4 = (short*)(smem + 16896);        // [64][40]  =  5120 B
  short* Hs  = (short*)(smem + 22016);        // [64][40]  =  5120 B
  const int tid = threadIdx.x;
  const int row0 = blockIdx.x * 64;
  const int w = tid >> 6, lane = tid & 63;
  const int lm = lane & 15, lk = (lane >> 4) * 8;
  const int rquad = (lane >> 4) * 4;
  const int w4row = tid >> 2, w4seg = (tid & 3) * 8;
  const int qtr = lane >> 4, ql = lane & 15;

  // issue chunk-0 weight loads first: in flight across the whole gather
  bf16x8 pw3[4];
  bf16x8 pw4;
#pragma unroll
  for (int q = 0; q < 4; q++) pw3[q] = *(const bf16x8*)(W3c + q * 2048 + tid * 8);
  pw4 = *(const bf16x8*)(W4c + (size_t)w4row * 512 + w4seg);

  // ---- gather 64 z3 rows into Zs[64][256] (overlays all of smem) ----
  short* Zs = (short*)smem;
  for (int pass = 0; pass < 4; pass++) {
    int nid = pass * 16 + w * 4 + qtr;       // 0..63, all distinct across block
    int gr = row0 + nid;
    float a[16];
    if (gr < M) {
      float di = dis[gr];
      int e0 = off[gr], e1 = off[gr + 1];
      const short* base = h2 + (size_t)gr * 256 + ql * 16;
      bf16x8 s0 = *(const bf16x8*)base;
      bf16x8 s1 = *(const bf16x8*)(base + 8);
#pragma unroll
      for (int j = 0; j < 8; j++) { a[j] = bf2f((unsigned short)s0[j]); a[8 + j] = bf2f((unsigned short)s1[j]); }
      int e = e0;
      for (; e + 8 <= e1; e += 8) {
        const short* p0 = h2 + (size_t)csr[e]     * 256 + ql * 16;
        const short* p1 = h2 + (size_t)csr[e + 1] * 256 + ql * 16;
        const short* p2 = h2 + (size_t)csr[e + 2] * 256 + ql * 16;
        const short* p3 = h2 + (size_t)csr[e + 3] * 256 + ql * 16;
        const short* p4 = h2 + (size_t)csr[e + 4] * 256 + ql * 16;
        const short* p5 = h2 + (size_t)csr[e + 5] * 256 + ql * 16;
        const short* p6 = h2 + (size_t)csr[e + 6] * 256 + ql * 16;
        const short* p7 = h2 + (size_t)csr[e + 7] * 256 + ql * 16;
        bf16x8 t00 = *(const bf16x8*)p0, t01 = *(const bf16x8*)(p0 + 8);
        bf16x8 t10 = *(const bf16x8*)p1, t11 = *(const bf16x8*)(p1 + 8);
        bf16x8 t20 = *(const bf16x8*)p2, t21 = *(const bf16x8*)(p2 + 8);
        bf16x8 t30 = *(const bf16x8*)p3, t31 = *(const bf16x8*)(p3 + 8);
        bf16x8 t40 = *(const bf16x8*)p4, t41 = *(const bf16x8*)(p4 + 8);
        bf16x8 t50 = *(const bf16x8*)p5, t51 = *(const bf16x8*)(p5 + 8);
        bf16x8 t60 = *(const bf16x8*)p6, t61 = *(const bf16x8*)(p6 + 8);
        bf16x8 t70 = *(const bf16x8*)p7, t71 = *(const bf16x8*)(p7 + 8);
#pragma unroll
        for (int j = 0; j < 8; j++) {
          a[j]     += ((bf2f((unsigned short)t00[j]) + bf2f((unsigned short)t10[j])) +
                       (bf2f((unsigned short)t20[j]) + bf2f((unsigned short)t30[j]))) +
                      ((bf2f((unsigned short)t40[j]) + bf2f((unsigned short)t50[j])) +
                       (bf2f((unsigned short)t60[j]) + bf2f((unsigned short)t70[j])));
          a[8 + j] += ((bf2f((unsigned short)t01[j]) + bf2f((unsigned short)t11[j])) +
                       (bf2f((unsigned short)t21[j]) + bf2f((unsigned short)t31[j]))) +
                      ((bf2f((unsigned short)t41[j]) + bf2f((unsigned short)t51[j])) +
                       (bf2f((unsigned short)t61[j]) + bf2f((unsigned short)t71[j])));
        }
      }
      for (; e + 4 <= e1; e += 4) {
        const short* p0 = h2 + (size_t)csr[e]     * 256 + ql * 16;
        const short* p1 = h2 + (size_t)csr[e + 1] * 256 + ql * 16;
        const short* p2 = h2 + (size_t)csr[e + 2] * 256 + ql * 16;
        const short* p3 = h2 + (size_t)csr[e + 3] * 256 + ql * 16;
        bf16x8 t00 = *(const bf16x8*)p0, t01 = *(const bf16x8*)(p0 + 8);
        bf16x8 t10 = *(const bf16x8*)p1, t11 = *(const bf16x8*)(p1 + 8);
        bf16x8 t20 = *(const bf16x8*)p2, t21 = *(const bf16x8*)(p2 + 8);
        bf16x8 t30 = *(const bf16x8*)p3, t31 = *(const bf16x8*)(p3 + 8);
#pragma unroll
        for (int j = 0; j < 8; j++) {
          a[j] += (bf2f((unsigned short)t00[j]) + bf2f((unsigned short)t10[j])) +
                  (bf2f((unsigned short)t20[j]) + bf2f((unsigned short)t30[j]));
          a[8 + j] += (bf2f((unsigned short)t01[j]) + bf2f((unsigned short)t11[j])) +
                      (bf2f((unsigned short)t21[j]) + bf2f((unsigned short)t31[j]));
        }
      }
      for (; e < e1; e++) {
        const short* p = h2 + (size_t)csr[e] * 256 + ql * 16;
        bf16x8 t0 = *(const bf16x8*)p, t1 = *(const bf16x8*)(p + 8);
#pragma unroll
        for (int j = 0; j < 8; j++) {
          a[j] += bf2f((unsigned short)t0[j]);
          a[8 + j] += bf2f((unsigned short)t1[j]);
        }
      }
#pragma unroll
      for (int j = 0; j < 16; j++) a[j] *= di;
    } else {
#pragma unroll
      for (int j = 0; j < 16; j++) a[j] = 0.f;
    }
    bf16x8 o0, o1;
#pragma unroll
    for (int j = 0; j < 8; j++) {
      o0[j] = (short)f2bf(a[j]);
      o1[j] = (short)f2bf(a[8 + j]);
    }
    *(bf16x8*)&Zs[nid * 256 + ql * 16] = o0;
    *(bf16x8*)&Zs[nid * 256 + ql * 16 + 8] = o1;
  }
  __syncthreads();

  // A fragments from Zs (one-time 16-way-conflicted read; negligible)
  bf16x8 afr[8];
  {
    int lr = w * 16 + lm;
#pragma unroll
    for (int kc = 0; kc < 8; kc++)
      afr[kc] = *(const bf16x8*)&Zs[lr * 256 + kc * 32 + lk];
  }
  __syncthreads();

  // write chunk 0 (pw regs loaded before the gather)
#pragma unroll
  for (int q = 0; q < 4; q++) {
    int flat = q * 2048 + tid * 8;
    *(bf16x8*)&Bs[(flat >> 8) * 264 + (flat & 255)] = pw3[q];
  }
  *(bf16x8*)&Ws4[w4row * 40 + w4seg] = pw4;
  __syncthreads();

  f32x4 t4acc[4];
#pragma unroll
  for (int nt = 0; nt < 4; nt++)
#pragma unroll
    for (int r = 0; r < 4; r++) t4acc[nt][r] = 0.f;

  for (int c = 0; c < 16; c++) {
    if (c < 15) {
#pragma unroll
      for (int q = 0; q < 4; q++) {
        int flat = q * 2048 + tid * 8;
        pw3[q] = *(const bf16x8*)(W3c + (size_t)(c + 1) * 8192 + flat);
      }
      pw4 = *(const bf16x8*)(W4c + (size_t)w4row * 512 + (c + 1) * 32 + w4seg);
    }

    f32x4 acc1[2];
#pragma unroll
    for (int nt = 0; nt < 2; nt++)
#pragma unroll
      for (int r = 0; r < 4; r++) acc1[nt][r] = 0.f;
#pragma unroll
    for (int k0 = 0; k0 < 8; k0++) {
      bf16x8 bb[2];
#pragma unroll
      for (int nt = 0; nt < 2; nt++) bb[nt] = *(const bf16x8*)&Bs[(nt * 16 + lm) * 264 + k0 * 32 + lk];
#pragma unroll
      for (int nt = 0; nt < 2; nt++)
        acc1[nt] = __builtin_amdgcn_mfma_f32_16x16x32_bf16(afr[k0], bb[nt], acc1[nt], 0, 0, 0);
    }
#pragma unroll
    for (int nt = 0; nt < 2; nt++) {
      float bv = b3[c * 32 + nt * 16 + lm];
#pragma unroll
      for (int r = 0; r < 4; r++) {
        float v = acc1[nt][r] + bv;
        v = (v >= 0.f) ? v : 0.01f * v;
        Hs[(w * 16 + rquad + r) * 40 + nt * 16 + lm] = (short)f2bf(v);
      }
    }
    {
      bf16x8 ah2 = *(const bf16x8*)&Hs[(w * 16 + lm) * 40 + lk];
      bf16x8 bb2[4];
#pragma unroll
      for (int nt = 0; nt < 4; nt++) bb2[nt] = *(const bf16x8*)&Ws4[(nt * 16 + lm) * 40 + lk];
#pragma unroll
      for (int nt = 0; nt < 4; nt++)
        t4acc[nt] = __builtin_amdgcn_mfma_f32_16x16x32_bf16(ah2, bb2[nt], t4acc[nt], 0, 0, 0);
    }
    __syncthreads();                         // all consumers of chunk c done
    if (c < 15) {
#pragma unroll
      for (int q = 0; q < 4; q++) {
        int flat = q * 2048 + tid * 8;
        *(bf16x8*)&Bs[(flat >> 8) * 264 + (flat & 255)] = pw3[q];
      }
      *(bf16x8*)&Ws4[w4row * 40 + w4seg] = pw4;
    }
    __syncthreads();                         // chunk c+1 visible
  }

  short* epi = (short*)smem;                 // 64*64 shorts = 8 KB
#pragma unroll
  for (int r = 0; r < 4; r++) {
    int lr = w * 16 + rquad + r;
    int gr = row0 + lr;
    float sc = (gr < M) ? dis[gr] : 0.f;
#pragma unroll
    for (int nt = 0; nt < 4; nt++)
      epi[lr * 64 + nt * 16 + lm] = (short)f2bf(t4acc[nt][r] * sc);
  }
  __syncthreads();
  {
    int base = tid * 16;
    int row = base >> 6, col = base & 63;
    int gr = row0 + row;
    if (gr < M) {
      *(bf16x8*)(T4 + (size_t)gr * 64 + col)     = *(bf16x8*)&epi[base];
      *(bf16x8*)(T4 + (size_t)gr * 64 + col + 8) = *(bf16x8*)&epi[base + 8];
    }
  }
}

// ------- Aggregation (dis-free; rows pre-scaled). Quad-node: 4 nodes/wave. -------
// Lane quarter q -> node 4w+q; each lane covers 4 features (8B, uint2).

template<int BR, int OSCL>
__global__ __launch_bounds__(256) void aggb64_k(const short* __restrict__ T, const float* __restrict__ dis,
                                                const int* __restrict__ off, const int* __restrict__ csr,
                                                const float* __restrict__ bias, short* __restrict__ Out, int n) {
  int wv = (blockIdx.x * 256 + threadIdx.x) >> 6;
  int lane = threadIdx.x & 63;
  int qtr = lane >> 4, ql = lane & 15;
  int wid = wv * 4 + qtr;
  if (wid >= n) return;
  float di = dis[wid];
  int e0 = off[wid], e1 = off[wid + 1];
  const uint2* Tw = (const uint2*)T;   // 4 bf16 per uint2; row = 16 uint2
  uint2 su = Tw[(size_t)wid * 16 + ql];
  float a0 = bflo(su.x), a1 = bfhi(su.x), a2 = bflo(su.y), a3 = bfhi(su.y);
  int e = e0;
  for (; e + 8 <= e1; e += 8) {
    uint2 u0 = Tw[(size_t)csr[e]     * 16 + ql];
    uint2 u1 = Tw[(size_t)csr[e + 1] * 16 + ql];
    uint2 u2 = Tw[(size_t)csr[e + 2] * 16 + ql];
    uint2 u3 = Tw[(size_t)csr[e + 3] * 16 + ql];
    uint2 u4 = Tw[(size_t)csr[e + 4] * 16 + ql];
    uint2 u5 = Tw[(size_t)csr[e + 5] * 16 + ql];
    uint2 u6 = Tw[(size_t)csr[e + 6] * 16 + ql];
    uint2 u7 = Tw[(size_t)csr[e + 7] * 16 + ql];
    a0 += ((bflo(u0.x) + bflo(u1.x)) + (bflo(u2.x) + bflo(u3.x))) +
          ((bflo(u4.x) + bflo(u5.x)) + (bflo(u6.x) + bflo(u7.x)));
    a1 += ((bfhi(u0.x) + bfhi(u1.x)) + (bfhi(u2.x) + bfhi(u3.x))) +
          ((bfhi(u4.x) + bfhi(u5.x)) + (bfhi(u6.x) + bfhi(u7.x)));
    a2 += ((bflo(u0.y) + bflo(u1.y)) + (bflo(u2.y) + bflo(u3.y))) +
          ((bflo(u4.y) + bflo(u5.y)) + (bflo(u6.y) + bflo(u7.y)));
    a3 += ((bfhi(u0.y) + bfhi(u1.y)) + (bfhi(u2.y) + bfhi(u3.y))) +
          ((bfhi(u4.y) + bfhi(u5.y)) + (bfhi(u6.y) + bfhi(u7.y)));
  }
  for (; e + 4 <= e1; e += 4) {
    uint2 u0 = Tw[(size_t)csr[e]     * 16 + ql];
    uint2 u1 = Tw[(size_t)csr[e + 1] * 16 + ql];
    uint2 u2 = Tw[(size_t)csr[e + 2] * 16 + ql];
    uint2 u3 = Tw[(size_t)csr[e + 3] * 16 + ql];
    a0 += (bflo(u0.x) + bflo(u1.x)) + (bflo(u2.x) + bflo(u3.x));
    a1 += (bfhi(u0.x) + bfhi(u1.x)) + (bfhi(u2.x) + bfhi(u3.x));
    a2 += (bflo(u0.y) + bflo(u1.y)) + (bflo(u2.y) + bflo(u3.y));
    a3 += (bfhi(u0.y) + bfhi(u1.y)) + (bfhi(u2.y) + bfhi(u3.y));
  }
  for (; e < e1; e++) {
    uint2 u = Tw[(size_t)csr[e] * 16 + ql];
    a0 += bflo(u.x); a1 += bfhi(u.x); a2 += bflo(u.y); a3 += bfhi(u.y);
  }
  float v0 = di * a0, v1 = di * a1, v2 = di * a2, v3 = di * a3;
  if (BR) {
    v0 += bias[ql * 4];     v1 += bias[ql * 4 + 1];
    v2 += bias[ql * 4 + 2]; v3 += bias[ql * 4 + 3];
    v0 = (v0 >= 0.f) ? v0 : 0.01f * v0;
    v1 = (v1 >= 0.f) ? v1 : 0.01f * v1;
    v2 = (v2 >= 0.f) ? v2 : 0.01f * v2;
    v3 = (v3 >= 0.f) ? v3 : 0.01f * v3;
  }
  if (OSCL) { v0 *= di; v1 *= di; v2 *= di; v3 *= di; }
  uint2 o;
  o.x = (unsigned)f2bf(v0) | ((unsigned)f2bf(v1) << 16);
  o.y = (unsigned)f2bf(v2) | ((unsigned)f2bf(v3) << 16);
  ((uint2*)Out)[(size_t)wid * 16 + ql] = o;
}

// layer-4 tail (quad-node): hn = LN( leaky(di*sum(t4b) + b4) + resid )
// 16-lane LN reduction per quarter (shfl offsets 8/4/2/1 stay within the quarter).
__global__ __launch_bounds__(256) void agg64_ln_k(const short* __restrict__ T, const float* __restrict__ dis,
                                                  const int* __restrict__ off, const int* __restrict__ csr,
                                                  const float* __restrict__ bias, const float* __restrict__ resid,
                                                  const float* __restrict__ g, const float* __restrict__ b,
                                                  float* __restrict__ outh, int n) {
  int wv = (blockIdx.x * 256 + threadIdx.x) >> 6;
  int lane = threadIdx.x & 63;
  int qtr = lane >> 4, ql = lane & 15;
  int wid = wv * 4 + qtr;
  if (wid >= n) return;
  float di = dis[wid];
  int e0 = off[wid], e1 = off[wid + 1];
  const uint2* Tw = (const uint2*)T;
  uint2 su = Tw[(size_t)wid * 16 + ql];
  float a0 = bflo(su.x), a1 = bfhi(su.x), a2 = bflo(su.y), a3 = bfhi(su.y);
  int e = e0;
  for (; e + 8 <= e1; e += 8) {
    uint2 u0 = Tw[(size_t)csr[e]     * 16 + ql];
    uint2 u1 = Tw[(size_t)csr[e + 1] * 16 + ql];
    uint2 u2 = Tw[(size_t)csr[e + 2] * 16 + ql];
    uint2 u3 = Tw[(size_t)csr[e + 3] * 16 + ql];
    uint2 u4 = Tw[(size_t)csr[e + 4] * 16 + ql];
    uint2 u5 = Tw[(size_t)csr[e + 5] * 16 + ql];
    uint2 u6 = Tw[(size_t)csr[e + 6] * 16 + ql];
    uint2 u7 = Tw[(size_t)csr[e + 7] * 16 + ql];
    a0 += ((bflo(u0.x) + bflo(u1.x)) + (bflo(u2.x) + bflo(u3.x))) +
          ((bflo(u4.x) + bflo(u5.x)) + (bflo(u6.x) + bflo(u7.x)));
    a1 += ((bfhi(u0.x) + bfhi(u1.x)) + (bfhi(u2.x) + bfhi(u3.x))) +
          ((bfhi(u4.x) + bfhi(u5.x)) + (bfhi(u6.x) + bfhi(u7.x)));
    a2 += ((bflo(u0.y) + bflo(u1.y)) + (bflo(u2.y) + bflo(u3.y))) +
          ((bflo(u4.y) + bflo(u5.y)) + (bflo(u6.y) + bflo(u7.y)));
    a3 += ((bfhi(u0.y) + bfhi(u1.y)) + (bfhi(u2.y) + bfhi(u3.y))) +
          ((bfhi(u4.y) + bfhi(u5.y)) + (bfhi(u6.y) + bfhi(u7.y)));
  }
  for (; e + 4 <= e1; e += 4) {
    uint2 u0 = Tw[(size_t)csr[e]     * 16 + ql];
    uint2 u1 = Tw[(size_t)csr[e + 1] * 16 + ql];
    uint2 u2 = Tw[(size_t)csr[e + 2] * 16 + ql];
    uint2 u3 = Tw[(size_t)csr[e + 3] * 16 + ql];
    a0 += (bflo(u0.x) + bflo(u1.x)) + (bflo(u2.x) + bflo(u3.x));
    a1 += (bfhi(u0.x) + bfhi(u1.x)) + (bfhi(u2.x) + bfhi(u3.x));
    a2 += (bflo(u0.y) + bflo(u1.y)) + (bflo(u2.y) + bflo(u3.y));
    a3 += (bfhi(u0.y) + bfhi(u1.y)) + (bfhi(u2.y) + bfhi(u3.y));
  }
  for (; e < e1; e++) {
    uint2 u = Tw[(size_t)csr[e] * 16 + ql];
    a0 += bflo(u.x); a1 += bfhi(u.x); a2 += bflo(u.y); a3 += bfhi(u.y);
  }
  float4 rv = ((const float4*)resid)[(size_t)wid * 16 + ql];
  float v0 = di * a0 + bias[ql * 4];
  float v1 = di * a1 + bias[ql * 4 + 1];
  float v2 = di * a2 + bias[ql * 4 + 2];
  float v3 = di * a3 + bias[ql * 4 + 3];
  v0 = (v0 >= 0.f) ? v0 : 0.01f * v0;
  v1 = (v1 >= 0.f) ? v1 : 0.01f * v1;
  v2 = (v2 >= 0.f) ? v2 : 0.01f * v2;
  v3 = (v3 >= 0.f) ? v3 : 0.01f * v3;
  v0 += rv.x; v1 += rv.y; v2 += rv.z; v3 += rv.w;
  float s = (v0 + v1) + (v2 + v3);
  float ss = (v0 * v0 + v1 * v1) + (v2 * v2 + v3 * v3);
#pragma unroll
  for (int o = 8; o > 0; o >>= 1) {
    s += __shfl_xor(s, o);
    ss += __shfl_xor(ss, o);
  }
  float m = s * (1.f / 64.f);
  float var = ss * (1.f / 64.f) - m * m;
  float rs = rsqrtf(var + 1e-5f);
  float4 o4;
  o4.x = (v0 - m) * rs * g[ql * 4]     + b[ql * 4];
  o4.y = (v1 - m) * rs * g[ql * 4 + 1] + b[ql * 4 + 1];
  o4.z = (v2 - m) * rs * g[ql * 4 + 2] + b[ql * 4 + 2];
  o4.w = (v3 - m) * rs * g[ql * 4 + 3] + b[ql * 4 + 3];
  ((float4*)outh)[(size_t)wid * 16 + ql] = o4;
}

// ---------------- per-graph max pool + final MLP (fused, one block per graph) ----------------

__global__ __launch_bounds__(256) void pool_mlp_k(const float* __restrict__ hn,
                                                  const float* __restrict__ fc1W, const float* __restrict__ fc1b,
                                                  const float* __restrict__ fng, const float* __restrict__ fnb,
                                                  const float* __restrict__ fc2W, const float* __restrict__ fc2b,
                                                  float* __restrict__ out, int n) {
  const int G = 64;
  int g = blockIdx.x;
  int f = threadIdx.x & 63, c = threadIdx.x >> 6;
  long long s0 = ((long long)g * n + G - 1) / G;
  long long e0 = ((long long)(g + 1) * n + G - 1) / G;
  float m = -INFINITY;
  for (long long i = s0 + c; i < e0; i += 4) m = fmaxf(m, hn[(size_t)i * 64 + f]);
  __shared__ float red[4][64];
  __shared__ float ps[64], qs[64];
  red[c][f] = m;
  __syncthreads();
  if (c == 0) ps[f] = fmaxf(fmaxf(red[0][f], red[1][f]), fmaxf(red[2][f], red[3][f]));
  __syncthreads();
  if (threadIdx.x < 64) {
    int lane = threadIdx.x;
    float q = fc1b[lane];
#pragma unroll 8
    for (int k = 0; k < 64; k++) q = fmaf(ps[k], fc1W[k * 64 + lane], q);
    float s = q, ss = q * q;
#pragma unroll
    for (int o = 32; o > 0; o >>= 1) {
      s += __shfl_xor(s, o);
      ss += __shfl_xor(ss, o);
    }
    float mm = s * (1.f / 64.f);
    float var = ss * (1.f / 64.f) - mm * mm;
    float y = (q - mm) * rsqrtf(var + 1e-5f) * fng[lane] + fnb[lane];
    y = (y >= 0.f) ? y : 0.01f * y;
    qs[lane] = y;
    __builtin_amdgcn_wave_barrier();
    if (lane < 16) {
      float o = fc2b[lane];
#pragma unroll 8
      for (int k = 0; k < 64; k++) o = fmaf(qs[k], fc2W[k * 16 + lane], o);
      out[g * 16 + lane] = o;
    }
  }
}

// ---------------- launch ----------------

extern "C" void kernel_launch(void* const* d_in, const int* in_sizes, int n_in,
                              void* d_out, int out_size, void* d_ws, size_t ws_size,
                              hipStream_t stream) {
  const float* x   = (const float*)d_in[0];
  const int*   ei  = (const int*)d_in[1];
  const float* W1  = (const float*)d_in[3];
  const float* b1  = (const float*)d_in[4];
  const float* W2  = (const float*)d_in[5];
  const float* b2  = (const float*)d_in[6];
  const float* W3  = (const float*)d_in[7];
  const float* b3  = (const float*)d_in[8];
  const float* W4  = (const float*)d_in[9];
  const float* b4  = (const float*)d_in[10];
  const float* Wr  = (const float*)d_in[11];
  const float* br  = (const float*)d_in[12];
  const float* lng = (const float*)d_in[13];
  const float* lnb = (const float*)d_in[14];
  const float* f1W = (const float*)d_in[15];
  const float* f1b = (const float*)d_in[16];
  const float* fng = (const float*)d_in[17];
  const float* fnb = (const float*)d_in[18];
  const float* f2W = (const float*)d_in[19];
  const float* f2b = (const float*)d_in[20];

  int n = in_sizes[0] / 128;   // 50000
  int e = in_sizes[1] / 2;     // 400000
  const int* src = ei;
  const int* dst = ei + e;

  float* arena = (float*)d_ws;
  float* resid = arena;                              // [0, 64n)
  short* h2b   = (short*)(arena + (size_t)64 * n);   // [64n, 192n) : n x 256 bf16, live until fused34 done
  short* t4b   = (short*)(arena + (size_t)192 * n);  // [192n, 224n): n x 64 bf16
  float* hn    = arena + (size_t)224 * n;            // [224n, 288n): n x 64 f32
  short* t1b   = (short*)(arena + (size_t)320 * n);
  short* h1b   = (short*)(arena + (size_t)352 * n);
  short* z2b   = (short*)(arena + (size_t)384 * n);
  float* dis   = arena + (size_t)448 * n;  // n
  int* cnt    = (int*)(dis + n);           // n
  int* off    = cnt + n;                   // n+1
  int* cursor = off + n + 1;               // n
  int* csr    = cursor + n;                // e
  int* bsum   = csr + e;                   // 256
  int* bpre   = bsum + 256;                // 256
  float* pool = (float*)(bpre + 256);      // layout keep
  size_t wq = (((size_t)(pool + 4096)) + 15) & ~(size_t)15;
  short* wc1 = (short*)wq;                 // 64 x 128   (wc1||wcR = fused 128 x 128)
  short* wcR = wc1 + 8192;                 // 64 x 128
  short* wc2 = wcR + 8192;                 // 256 x 64
  short* wc3 = wc2 + 16384;                // 512 x 256
  short* wc4 = wc3 + 131072;               // 64 x 512
  size_t need = ((char*)(wc4 + 32768) - (char*)d_ws) + 64;
  if (ws_size < need) return;

  int nb_n = (n + 255) / 256;        // 196
  int nb_e = (e + 255) / 256;
  int nb_w4 = ((n + 3) / 4 + 3) / 4; // four nodes per wave
  int g_wide = (n + 63) / 64;        // 782
  int g_fused = (n + 127) / 128;     // 391

  // weights -> bf16 [N][K]
  wconv_k<<<960, 256, 0, stream>>>(W1, Wr, W2, W3, W4, wc1, wcR, wc2, wc3, wc4);

  // degree + CSR (hierarchical scan; dis fused into scan_c)
  hipMemsetAsync(cnt, 0, (size_t)n * sizeof(int), stream);
  count_k<<<nb_e, 256, 0, stream>>>(dst, cnt, e);
  scan_a<<<nb_n, 256, 0, stream>>>(cnt, bsum, n);
  scan_b<<<1, 256, 0, stream>>>(bsum, bpre, off + n, nb_n);
  scan_c<<<nb_n, 256, 0, stream>>>(cnt, bpre, off, cursor, dis, n);
  scatter_k<<<nb_e, 256, 0, stream>>>(src, dst, cursor, csr, e);

  // fused L1 + residual: t1b = bf16(dis*(x@W1)); resid = x@Wr + br
  mgemm<128, 128, 2, 2, 1, 0, 0, 0, 1, 1, 4><<<dim3(g_fused, 1), 256, 0, stream>>>(x, wc1, br, t1b, resid, dis, n);
  // h1b = bf16( dis * leaky(di*sum(t1) + b1) )
  aggb64_k<1, 1><<<nb_w4, 256, 0, stream>>>(t1b, dis, off, csr, b1, h1b, n);
  // z2b = bf16( di * sum(h1) )
  aggb64_k<0, 0><<<nb_w4, 256, 0, stream>>>(h1b, dis, off, csr, nullptr, z2b, n);
  // h2b = bf16( dis * leaky(z2@W2 + b2) )
  mgemm<64, 256, 1, 4, 1, 1, 1, 1, 0, 1, 5><<<dim3(g_wide, 1), 256, 0, stream>>>(z2b, wc2, b2, h2b, nullptr, dis, n);
  // t4b = bf16( dis * (leaky(agg256(h2b)@W3+b3) @ W4) )   (agg256 + L3 + L4 fused, v8)
  fused34_k<<<g_wide, 256, 0, stream>>>(h2b, off, csr, wc3, b3, wc4, dis, t4b, n);
  // hn = LN( leaky(di*sum(t4b) + b4) + resid )   (quad-node)
  agg64_ln_k<<<nb_w4, 256, 0, stream>>>(t4b, dis, off, csr, b4, resid, lng, lnb, hn, n);
  // pool + MLP fused
  pool_mlp_k<<<64, 256, 0, stream>>>(hn, f1W, f1b, fng, fnb, f2W, f2b, (float*)d_out, n);
}